// Round 14
// baseline (110.691 us; speedup 1.0000x reference)
//
#include <hip/hip_runtime.h>
#include <hip/hip_bf16.h>
#include <stdint.h>

// Problem constants
#define BB 8
#define CC 64
#define NN 16384
#define KNB 8            // neighbors
// Padded GEMM1 K (REPERMUTED): cols kk*64+c = feature[c][idx[kk]] for kk=0..7,
// cols 512..519 = dis[0..7], cols 520..543 = 0.  (17 kb-steps of 32)

typedef __attribute__((ext_vector_type(8))) short   s16x8;
typedef __attribute__((ext_vector_type(4))) short   s16x4;
typedef __attribute__((ext_vector_type(8))) __bf16  bf16x8;
typedef __attribute__((ext_vector_type(4))) float   f32x4;

__device__ __forceinline__ unsigned short f2bf(float f) {
    unsigned u = __builtin_bit_cast(unsigned, f);
    u = (u + 0x7FFFu + ((u >> 16) & 1u)) >> 16;   // RNE, inputs finite
    return (unsigned short)u;
}

__device__ __forceinline__ int getq(const int4& q, int j) {
    return j == 0 ? q.x : j == 1 ? q.y : j == 2 ? q.z : q.w;   // j constant-folds after unroll
}

// ---- workspace layout (bytes) ----
#define OFF_DISB  16777216u
#define OFF_W1B   18874368u
#define OFF_W2B   19013632u
#define OFF_W3B   19046400u

// ---------------- merged prep: featT transpose + dis->bf16 + weights frag-major ----------------
__global__ __launch_bounds__(256) void prep_all(
    const float* __restrict__ feat, const float* __restrict__ dis,
    const float* __restrict__ W1, const float* __restrict__ W2, const float* __restrict__ W3,
    unsigned short* __restrict__ featT, unsigned short* __restrict__ disB,
    unsigned short* __restrict__ w1p, unsigned short* __restrict__ w2p,
    unsigned short* __restrict__ w3p)
{
    const int bid = blockIdx.x;
    if (bid < 512) {
        int gt = bid * 256 + threadIdx.x;          // global point 0..131071
        int b = gt >> 14, n = gt & 16383;
        const float* fp = feat + ((size_t)b << 20) + n;
        unsigned short v[64];
        #pragma unroll
        for (int c = 0; c < 64; ++c) v[c] = f2bf(fp[(size_t)c << 14]);  // coalesced across lanes
        unsigned short* dst = featT + (size_t)gt * 64;
        #pragma unroll
        for (int j = 0; j < 8; ++j) {
            s16x8 pk;
            #pragma unroll
            for (int i = 0; i < 8; ++i) pk[i] = (short)v[j * 8 + i];
            *(s16x8*)(dst + j * 8) = pk;
        }
        return;
    }
    int tid = (bid - 512) * 256 + threadIdx.x;
    if (tid < 131072) {                        // one POINT per thread: 8 dis values
        const float* dp = dis + (size_t)tid * 8;
        s16x8 pk;
        #pragma unroll
        for (int j = 0; j < 8; ++j) pk[j] = (short)f2bf(dp[j]);
        *(s16x8*)(disB + (size_t)tid * 8) = pk;
        return;
    }
    int t2 = tid - 131072;
    if (t2 < 8704) {                           // W1p: kb 0..16, t 0..7, lane 0..63
        int kb   = t2 >> 9;
        int rem  = t2 & 511;
        int t    = rem >> 6;
        int lane = rem & 63;
        int row  = t * 16 + (lane & 15);
        int kbase = kb * 32 + (lane >> 4) * 8;
        s16x8 pk;
        #pragma unroll
        for (int j = 0; j < 8; ++j) {
            int kp = kbase + j;
            float val = 0.f;
            if (kp < 512) {                                          // feature weights
                int kk = kp >> 6, c = kp & 63;
                val = W1[row * 520 + kk * 65 + 1 + c];
            } else if (kp < 520) {                                   // dis weight of neighbor kp-512
                val = W1[row * 520 + (kp - 512) * 65];
            }
            pk[j] = (short)f2bf(val);
        }
        *(s16x8*)(w1p + (size_t)t2 * 8) = pk;
    } else if (t2 < 8704 + 2048) {             // W2p
        int f    = t2 - 8704;
        int kb   = f >> 9;
        int rem  = f & 511;
        int t    = rem >> 6;
        int lane = rem & 63;
        int row  = t * 16 + (lane & 15);
        int k    = kb * 32 + (lane >> 4) * 8;
        s16x8 pk;
        #pragma unroll
        for (int j = 0; j < 8; ++j) pk[j] = (short)f2bf(W2[row * 128 + k + j]);
        *(s16x8*)(w2p + (size_t)f * 8) = pk;
    } else if (t2 < 8704 + 2048 + 4096) {      // W3p
        int f    = t2 - 10752;
        int hk   = f >> 9;
        int half = hk >> 2, kb = hk & 3;
        int rem  = f & 511;
        int t    = rem >> 6;
        int lane = rem & 63;
        int row  = (half * 8 + t) * 16 + (lane & 15);
        int k    = kb * 32 + (lane >> 4) * 8;
        s16x8 pk;
        #pragma unroll
        for (int j = 0; j < 8; ++j) pk[j] = (short)f2bf(W3[row * 128 + k + j]);
        *(s16x8*)(w3p + (size_t)f * 8) = pk;
    }
}

// ---------------- main fused kernel helpers ----------------
// Weight fragments: nontemporal (L1-bypass). Weights are single-use per wave
// (8 waves x 237KB streams >> 32KB L1 -> ~0% hits) and evict gather lines.
// nt keeps L1 free so even/odd gather pairs (same 128B featT line, 1 step apart)
// can hit L1 on the odd step.
__device__ __forceinline__ void wload4(const unsigned short* wp, int frag0, int lane,
                                       bf16x8& w0, bf16x8& w1, bf16x8& w2, bf16x8& w3)
{
    w0 = __builtin_nontemporal_load((const bf16x8*)(wp + (size_t)((frag0 + 0) * 64 + lane) * 8));
    w1 = __builtin_nontemporal_load((const bf16x8*)(wp + (size_t)((frag0 + 1) * 64 + lane) * 8));
    w2 = __builtin_nontemporal_load((const bf16x8*)(wp + (size_t)((frag0 + 2) * 64 + lane) * 8));
    w3 = __builtin_nontemporal_load((const bf16x8*)(wp + (size_t)((frag0 + 3) * 64 + lane) * 8));
}

// iq[] holds the CURRENT half of each point's idx row; swapped at the kb 7->8 boundary.
template <int KB>
__device__ __forceinline__ void gather4(const unsigned short* featB, const int4 (&iq)[4],
                                        int grp8, bf16x8& G0, bf16x8& G1, bf16x8& G2, bf16x8& G3)
{
    constexpr int kk = KB >> 1;
    constexpr int j  = kk & 3;
    const int c0 = (KB & 1) * 32 + grp8;
    G0 = *(const bf16x8*)(featB + (((size_t)(unsigned)getq(iq[0], j)) << 6) + c0);
    G1 = *(const bf16x8*)(featB + (((size_t)(unsigned)getq(iq[1], j)) << 6) + c0);
    G2 = *(const bf16x8*)(featB + (((size_t)(unsigned)getq(iq[2], j)) << 6) + c0);
    G3 = *(const bf16x8*)(featB + (((size_t)(unsigned)getq(iq[3], j)) << 6) + c0);
}

__device__ __forceinline__ void refresh_iq(int4 (&iq)[4], const int* ip0) {
    #pragma unroll
    for (int pt = 0; pt < 4; ++pt) iq[pt] = *(const int4*)(ip0 + pt * 128 + 4);   // hi half (kk 4..7)
}

// dis columns (kb=16 data): grp 0 lanes carry dis[0..7], other grps are zero pad
__device__ __forceinline__ void disload4(const unsigned short* disB, int p0, int l15, int grp,
                                         bf16x8& G0, bf16x8& G1, bf16x8& G2, bf16x8& G3)
{
    const s16x8 z = {0,0,0,0,0,0,0,0};
    if (grp == 0) {
        G0 = *(const bf16x8*)(disB + (size_t)(p0 +  0 + l15) * 8);
        G1 = *(const bf16x8*)(disB + (size_t)(p0 + 16 + l15) * 8);
        G2 = *(const bf16x8*)(disB + (size_t)(p0 + 32 + l15) * 8);
        G3 = *(const bf16x8*)(disB + (size_t)(p0 + 48 + l15) * 8);
    } else {
        G0 = __builtin_bit_cast(bf16x8, z); G1 = __builtin_bit_cast(bf16x8, z);
        G2 = __builtin_bit_cast(bf16x8, z); G3 = __builtin_bit_cast(bf16x8, z);
    }
}

__device__ __forceinline__ void dsread4(const unsigned short* strip, int kb, int l15, int grp8,
                                        bf16x8& G0, bf16x8& G1, bf16x8& G2, bf16x8& G3)
{
    G0 = *(const bf16x8*)(strip + (0 * 16 + l15) * 136 + kb * 32 + grp8);
    G1 = *(const bf16x8*)(strip + (1 * 16 + l15) * 136 + kb * 32 + grp8);
    G2 = *(const bf16x8*)(strip + (2 * 16 + l15) * 136 + kb * 32 + grp8);
    G3 = *(const bf16x8*)(strip + (3 * 16 + l15) * 136 + kb * 32 + grp8);
}

// MFMA quad wrapped with s_setprio(1): waves are independent 1-wave blocks at
// staggered phases -> scheduler favors the MFMA-entering wave (T5 regime).
__device__ __forceinline__ void mfma_quad(f32x4 (&ac)[8][4], int t0,
    const bf16x8& wa, const bf16x8& wb, const bf16x8& wc, const bf16x8& wd,
    const bf16x8& B0, const bf16x8& B1, const bf16x8& B2, const bf16x8& B3)
{
    __builtin_amdgcn_s_setprio(1);
    ac[t0+0][0] = __builtin_amdgcn_mfma_f32_16x16x32_bf16(wa, B0, ac[t0+0][0], 0, 0, 0);
    ac[t0+0][1] = __builtin_amdgcn_mfma_f32_16x16x32_bf16(wa, B1, ac[t0+0][1], 0, 0, 0);
    ac[t0+0][2] = __builtin_amdgcn_mfma_f32_16x16x32_bf16(wa, B2, ac[t0+0][2], 0, 0, 0);
    ac[t0+0][3] = __builtin_amdgcn_mfma_f32_16x16x32_bf16(wa, B3, ac[t0+0][3], 0, 0, 0);
    ac[t0+1][0] = __builtin_amdgcn_mfma_f32_16x16x32_bf16(wb, B0, ac[t0+1][0], 0, 0, 0);
    ac[t0+1][1] = __builtin_amdgcn_mfma_f32_16x16x32_bf16(wb, B1, ac[t0+1][1], 0, 0, 0);
    ac[t0+1][2] = __builtin_amdgcn_mfma_f32_16x16x32_bf16(wb, B2, ac[t0+1][2], 0, 0, 0);
    ac[t0+1][3] = __builtin_amdgcn_mfma_f32_16x16x32_bf16(wb, B3, ac[t0+1][3], 0, 0, 0);
    ac[t0+2][0] = __builtin_amdgcn_mfma_f32_16x16x32_bf16(wc, B0, ac[t0+2][0], 0, 0, 0);
    ac[t0+2][1] = __builtin_amdgcn_mfma_f32_16x16x32_bf16(wc, B1, ac[t0+2][1], 0, 0, 0);
    ac[t0+2][2] = __builtin_amdgcn_mfma_f32_16x16x32_bf16(wc, B2, ac[t0+2][2], 0, 0, 0);
    ac[t0+2][3] = __builtin_amdgcn_mfma_f32_16x16x32_bf16(wc, B3, ac[t0+2][3], 0, 0, 0);
    ac[t0+3][0] = __builtin_amdgcn_mfma_f32_16x16x32_bf16(wd, B0, ac[t0+3][0], 0, 0, 0);
    ac[t0+3][1] = __builtin_amdgcn_mfma_f32_16x16x32_bf16(wd, B1, ac[t0+3][1], 0, 0, 0);
    ac[t0+3][2] = __builtin_amdgcn_mfma_f32_16x16x32_bf16(wd, B2, ac[t0+3][2], 0, 0, 0);
    ac[t0+3][3] = __builtin_amdgcn_mfma_f32_16x16x32_bf16(wd, B3, ac[t0+3][3], 0, 0, 0);
    __builtin_amdgcn_s_setprio(0);
}

// ---------------- main fused kernel ----------------
// 1 wave per block, 64 points per wave (R12 structure = session best, exact ordering).
// Software-pipelined: gathers 2-deep reg dbuf, weights quad-dbuf, zero barriers.
// GNEXT stays AFTER the second mfma_quad (WAR rule from R11).
__global__ __launch_bounds__(64, 2) void pointconv_main(
    const unsigned short* __restrict__ featT,
    const unsigned short* __restrict__ disB,
    const int* __restrict__ idx,
    const unsigned short* __restrict__ w1p,
    const unsigned short* __restrict__ w2p,
    const unsigned short* __restrict__ w3p,
    const float* __restrict__ b1, const float* __restrict__ b2,
    const float* __restrict__ b3, float* __restrict__ out)
{
    __shared__ __align__(16) unsigned short strip[64 * 136];   // 17,408 B
    const int bid  = blockIdx.x;
    const int wg   = (bid & 7) * 256 + (bid >> 3);     // XCD-aware bijective swizzle
    const int lane = threadIdx.x;                      // 0..63
    const int grp  = lane >> 4;
    const int grp8 = grp * 8;
    const int l15  = lane & 15;
    const int p0   = wg * 64;
    const int b    = p0 >> 14;
    const int n0   = p0 & 16383;

    // pipeline registers
    bf16x8 gA0, gA1, gA2, gA3, gB0, gB1, gB2, gB3;     // B-frag double buffer
    bf16x8 wA0, wA1, wA2, wA3, wB0, wB1, wB2, wB3;     // weight quad double buffer

    // ---- prolog: first weights, idx lo-half, first two gather sets ----
    wload4(w1p, 0, lane, wA0, wA1, wA2, wA3);          // Q(0,0)

    const int* ip0 = idx + (size_t)(p0 + l15) * 8;
    int4 iq[4];
    #pragma unroll
    for (int pt = 0; pt < 4; ++pt) iq[pt] = *(const int4*)(ip0 + pt * 128);   // kk 0..3

    const unsigned short* featB = featT + ((size_t)b << 20);

    gather4<0>(featB, iq, grp8, gA0, gA1, gA2, gA3);
    gather4<1>(featB, iq, grp8, gB0, gB1, gB2, gB3);

    // ================= GEMM1: [128 x 544] * [544 x 64] =================
    f32x4 acc[8][4];
    #pragma unroll
    for (int t = 0; t < 8; ++t)
        #pragma unroll
        for (int pt = 0; pt < 4; ++pt) acc[t][pt] = (f32x4){0.f, 0.f, 0.f, 0.f};

// R12 ordering: wB load; quad1(wA,S); next-wA prefetch; quad2(wB,S); THEN gather into S's dbuf partner
#define G1_BODY(KB, S0,S1,S2,S3, WNEXT, GNEXT)                              \
    wload4(w1p, (KB)*8 + 4, lane, wB0, wB1, wB2, wB3);                      \
    mfma_quad(acc, 0, wA0, wA1, wA2, wA3, S0, S1, S2, S3);                  \
    WNEXT;                                                                  \
    mfma_quad(acc, 4, wB0, wB1, wB2, wB3, S0, S1, S2, S3);                  \
    GNEXT;

    G1_BODY(0,  gA0,gA1,gA2,gA3, wload4(w1p,  8, lane, wA0,wA1,wA2,wA3), (gather4< 2>(featB, iq, grp8, gA0,gA1,gA2,gA3)))
    G1_BODY(1,  gB0,gB1,gB2,gB3, wload4(w1p, 16, lane, wA0,wA1,wA2,wA3), (gather4< 3>(featB, iq, grp8, gB0,gB1,gB2,gB3)))
    G1_BODY(2,  gA0,gA1,gA2,gA3, wload4(w1p, 24, lane, wA0,wA1,wA2,wA3), (gather4< 4>(featB, iq, grp8, gA0,gA1,gA2,gA3)))
    G1_BODY(3,  gB0,gB1,gB2,gB3, wload4(w1p, 32, lane, wA0,wA1,wA2,wA3), (gather4< 5>(featB, iq, grp8, gB0,gB1,gB2,gB3)))
    G1_BODY(4,  gA0,gA1,gA2,gA3, wload4(w1p, 40, lane, wA0,wA1,wA2,wA3), (gather4< 6>(featB, iq, grp8, gA0,gA1,gA2,gA3)))
    G1_BODY(5,  gB0,gB1,gB2,gB3, wload4(w1p, 48, lane, wA0,wA1,wA2,wA3), (gather4< 7>(featB, iq, grp8, gB0,gB1,gB2,gB3)))
    refresh_iq(iq, ip0);                                // swap to hi half (kk 4..7)
    G1_BODY(6,  gA0,gA1,gA2,gA3, wload4(w1p, 56, lane, wA0,wA1,wA2,wA3), (gather4< 8>(featB, iq, grp8, gA0,gA1,gA2,gA3)))
    G1_BODY(7,  gB0,gB1,gB2,gB3, wload4(w1p, 64, lane, wA0,wA1,wA2,wA3), (gather4< 9>(featB, iq, grp8, gB0,gB1,gB2,gB3)))
    G1_BODY(8,  gA0,gA1,gA2,gA3, wload4(w1p, 72, lane, wA0,wA1,wA2,wA3), (gather4<10>(featB, iq, grp8, gA0,gA1,gA2,gA3)))
    G1_BODY(9,  gB0,gB1,gB2,gB3, wload4(w1p, 80, lane, wA0,wA1,wA2,wA3), (gather4<11>(featB, iq, grp8, gB0,gB1,gB2,gB3)))
    G1_BODY(10, gA0,gA1,gA2,gA3, wload4(w1p, 88, lane, wA0,wA1,wA2,wA3), (gather4<12>(featB, iq, grp8, gA0,gA1,gA2,gA3)))
    G1_BODY(11, gB0,gB1,gB2,gB3, wload4(w1p, 96, lane, wA0,wA1,wA2,wA3), (gather4<13>(featB, iq, grp8, gB0,gB1,gB2,gB3)))
    G1_BODY(12, gA0,gA1,gA2,gA3, wload4(w1p,104, lane, wA0,wA1,wA2,wA3), (gather4<14>(featB, iq, grp8, gA0,gA1,gA2,gA3)))
    G1_BODY(13, gB0,gB1,gB2,gB3, wload4(w1p,112, lane, wA0,wA1,wA2,wA3), (gather4<15>(featB, iq, grp8, gB0,gB1,gB2,gB3)))
    // kb=14: "next gather" slot loads the dis columns (kb=16 data) into the gA set
    G1_BODY(14, gA0,gA1,gA2,gA3, wload4(w1p,120, lane, wA0,wA1,wA2,wA3), disload4(disB, p0, l15, grp, gA0,gA1,gA2,gA3))
    G1_BODY(15, gB0,gB1,gB2,gB3, wload4(w1p,128, lane, wA0,wA1,wA2,wA3), )
    // kb=16 (dis/zero cols); next-weight prefetch chains into GEMM2's first quad
    G1_BODY(16, gA0,gA1,gA2,gA3, wload4(w2p, 0, lane, wA0,wA1,wA2,wA3), )
#undef G1_BODY

    // epilogue 1: bias + relu -> strip[pt][ch] bf16
    #pragma unroll
    for (int t = 0; t < 8; ++t) {
        const int chb = t * 16 + grp * 4;
        const float4 bv = *(const float4*)(b1 + chb);
        #pragma unroll
        for (int pt = 0; pt < 4; ++pt) {
            s16x4 pk;
            float v0 = acc[t][pt][0] + bv.x; pk[0] = (short)f2bf(v0 > 0.f ? v0 : 0.f);
            float v1 = acc[t][pt][1] + bv.y; pk[1] = (short)f2bf(v1 > 0.f ? v1 : 0.f);
            float v2 = acc[t][pt][2] + bv.z; pk[2] = (short)f2bf(v2 > 0.f ? v2 : 0.f);
            float v3 = acc[t][pt][3] + bv.w; pk[3] = (short)f2bf(v3 > 0.f ? v3 : 0.f);
            *(s16x4*)(strip + (pt * 16 + l15) * 136 + chb) = pk;
        }
    }

    // ================= GEMM2: [128 x 128] * [128 x 64] =================
    f32x4 acc2[8][4];
    #pragma unroll
    for (int t = 0; t < 8; ++t)
        #pragma unroll
        for (int pt = 0; pt < 4; ++pt) acc2[t][pt] = (f32x4){0.f, 0.f, 0.f, 0.f};

    dsread4(strip, 0, l15, grp8, gA0, gA1, gA2, gA3);

#define G23_BODY(WP, FR, S0,S1,S2,S3, ACC, WNEXT, DSNEXT)                   \
    wload4(WP, (FR) + 4, lane, wB0, wB1, wB2, wB3);                         \
    mfma_quad(ACC, 0, wA0, wA1, wA2, wA3, S0, S1, S2, S3);                  \
    WNEXT;                                                                  \
    DSNEXT;                                                                 \
    mfma_quad(ACC, 4, wB0, wB1, wB2, wB3, S0, S1, S2, S3);

    G23_BODY(w2p,  0, gA0,gA1,gA2,gA3, acc2, wload4(w2p,  8, lane, wA0,wA1,wA2,wA3), dsread4(strip, 1, l15, grp8, gB0,gB1,gB2,gB3))
    G23_BODY(w2p,  8, gB0,gB1,gB2,gB3, acc2, wload4(w2p, 16, lane, wA0,wA1,wA2,wA3), dsread4(strip, 2, l15, grp8, gA0,gA1,gA2,gA3))
    G23_BODY(w2p, 16, gA0,gA1,gA2,gA3, acc2, wload4(w2p, 24, lane, wA0,wA1,wA2,wA3), dsread4(strip, 3, l15, grp8, gB0,gB1,gB2,gB3))
    G23_BODY(w2p, 24, gB0,gB1,gB2,gB3, acc2, wload4(w3p,  0, lane, wA0,wA1,wA2,wA3), )

    // epilogue 2: bias + relu -> strip (H1 fully consumed; same-wave ordering)
    #pragma unroll
    for (int t = 0; t < 8; ++t) {
        const int chb = t * 16 + grp * 4;
        const float4 bv = *(const float4*)(b2 + chb);
        #pragma unroll
        for (int pt = 0; pt < 4; ++pt) {
            s16x4 pk;
            float v0 = acc2[t][pt][0] + bv.x; pk[0] = (short)f2bf(v0 > 0.f ? v0 : 0.f);
            float v1 = acc2[t][pt][1] + bv.y; pk[1] = (short)f2bf(v1 > 0.f ? v1 : 0.f);
            float v2 = acc2[t][pt][2] + bv.z; pk[2] = (short)f2bf(v2 > 0.f ? v2 : 0.f);
            float v3 = acc2[t][pt][3] + bv.w; pk[3] = (short)f2bf(v3 > 0.f ? v3 : 0.f);
            *(s16x4*)(strip + (pt * 16 + l15) * 136 + chb) = pk;
        }
    }

    // ================= GEMM3: [256 x 128] * [128 x 64], two halves =================
    #pragma unroll
    for (int half = 0; half < 2; ++half) {
        f32x4 acc3[8][4];
        #pragma unroll
        for (int t = 0; t < 8; ++t)
            #pragma unroll
            for (int pt = 0; pt < 4; ++pt) acc3[t][pt] = (f32x4){0.f, 0.f, 0.f, 0.f};

        dsread4(strip, 0, l15, grp8, gA0, gA1, gA2, gA3);
        if (half == 0) {
            G23_BODY(w3p,  0, gA0,gA1,gA2,gA3, acc3, wload4(w3p,  8, lane, wA0,wA1,wA2,wA3), dsread4(strip, 1, l15, grp8, gB0,gB1,gB2,gB3))
            G23_BODY(w3p,  8, gB0,gB1,gB2,gB3, acc3, wload4(w3p, 16, lane, wA0,wA1,wA2,wA3), dsread4(strip, 2, l15, grp8, gA0,gA1,gA2,gA3))
            G23_BODY(w3p, 16, gA0,gA1,gA2,gA3, acc3, wload4(w3p, 24, lane, wA0,wA1,wA2,wA3), dsread4(strip, 3, l15, grp8, gB0,gB1,gB2,gB3))
            G23_BODY(w3p, 24, gB0,gB1,gB2,gB3, acc3, wload4(w3p, 32, lane, wA0,wA1,wA2,wA3), )
        } else {
            G23_BODY(w3p, 32, gA0,gA1,gA2,gA3, acc3, wload4(w3p, 40, lane, wA0,wA1,wA2,wA3), dsread4(strip, 1, l15, grp8, gB0,gB1,gB2,gB3))
            G23_BODY(w3p, 40, gB0,gB1,gB2,gB3, acc3, wload4(w3p, 48, lane, wA0,wA1,wA2,wA3), dsread4(strip, 2, l15, grp8, gA0,gA1,gA2,gA3))
            G23_BODY(w3p, 48, gA0,gA1,gA2,gA3, acc3, wload4(w3p, 56, lane, wA0,wA1,wA2,wA3), dsread4(strip, 3, l15, grp8, gB0,gB1,gB2,gB3))
            G23_BODY(w3p, 56, gB0,gB1,gB2,gB3, acc3, , )
        }

        #pragma unroll
        for (int t = 0; t < 8; ++t) {
            const int chb = half * 128 + t * 16 + grp * 4;
            const float4 bv = *(const float4*)(b3 + chb);
            #pragma unroll
            for (int pt = 0; pt < 4; ++pt) {
                const int n = n0 + pt * 16 + l15;
                float* op = out + (((size_t)(b * 256 + chb)) << 14) + n;
                op[0]                  = acc3[t][pt][0] + bv.x;
                op[(size_t)1 << 14]    = acc3[t][pt][1] + bv.y;
                op[(size_t)2 << 14]    = acc3[t][pt][2] + bv.z;
                op[(size_t)3 << 14]    = acc3[t][pt][3] + bv.w;
            }
        }
    }
#undef G23_BODY
}

extern "C" void kernel_launch(void* const* d_in, const int* in_sizes, int n_in,
                              void* d_out, int out_size, void* d_ws, size_t ws_size,
                              hipStream_t stream)
{
    const float* feature = (const float*)d_in[0];
    const int*   idx     = (const int*)d_in[1];
    const float* dis     = (const float*)d_in[2];
    const float* W1      = (const float*)d_in[3];
    const float* b1      = (const float*)d_in[4];
    const float* W2      = (const float*)d_in[5];
    const float* b2      = (const float*)d_in[6];
    const float* W3      = (const float*)d_in[7];
    const float* b3      = (const float*)d_in[8];
    float* out = (float*)d_out;

    char* ws = (char*)d_ws;
    unsigned short* featT = (unsigned short*)ws;
    unsigned short* disB  = (unsigned short*)(ws + OFF_DISB);
    unsigned short* w1p   = (unsigned short*)(ws + OFF_W1B);
    unsigned short* w2p   = (unsigned short*)(ws + OFF_W2B);
    unsigned short* w3p   = (unsigned short*)(ws + OFF_W3B);

    hipLaunchKernelGGL(prep_all, dim3(1488), dim3(256), 0, stream,
                       feature, dis, W1, W2, W3, featT, disB, w1p, w2p, w3p);
    hipLaunchKernelGGL(pointconv_main, dim3(2048), dim3(64), 0, stream,
                       featT, disB, idx, w1p, w2p, w3p, b1, b2, b3, out);
}

// Round 15
// 73.065 us; speedup vs baseline: 1.5150x; 1.5150x over previous
//
#include <hip/hip_runtime.h>
#include <hip/hip_bf16.h>
#include <stdint.h>

// Problem constants
#define BB 8
#define CC 64
#define NN 16384
#define KNB 8            // neighbors
// Padded GEMM1 K (REPERMUTED): cols kk*64+c = feature[c][idx[kk]] for kk=0..7,
// cols 512..519 = dis[0..7], cols 520..543 = 0.  (17 kb-steps of 32)

typedef __attribute__((ext_vector_type(8))) short   s16x8;
typedef __attribute__((ext_vector_type(4))) short   s16x4;
typedef __attribute__((ext_vector_type(8))) __bf16  bf16x8;
typedef __attribute__((ext_vector_type(4))) float   f32x4;

__device__ __forceinline__ unsigned short f2bf(float f) {
    unsigned u = __builtin_bit_cast(unsigned, f);
    u = (u + 0x7FFFu + ((u >> 16) & 1u)) >> 16;   // RNE, inputs finite
    return (unsigned short)u;
}

__device__ __forceinline__ int getq(const int4& q, int j) {
    return j == 0 ? q.x : j == 1 ? q.y : j == 2 ? q.z : q.w;   // j constant-folds after unroll
}

// ---- workspace layout (bytes) ----
#define OFF_DISB  16777216u
#define OFF_W1B   18874368u
#define OFF_W2B   19013632u
#define OFF_W3B   19046400u

// ---------------- merged prep: featT transpose + dis->bf16 + weights frag-major ----------------
__global__ __launch_bounds__(256) void prep_all(
    const float* __restrict__ feat, const float* __restrict__ dis,
    const float* __restrict__ W1, const float* __restrict__ W2, const float* __restrict__ W3,
    unsigned short* __restrict__ featT, unsigned short* __restrict__ disB,
    unsigned short* __restrict__ w1p, unsigned short* __restrict__ w2p,
    unsigned short* __restrict__ w3p)
{
    const int bid = blockIdx.x;
    if (bid < 512) {
        int gt = bid * 256 + threadIdx.x;          // global point 0..131071
        int b = gt >> 14, n = gt & 16383;
        const float* fp = feat + ((size_t)b << 20) + n;
        unsigned short v[64];
        #pragma unroll
        for (int c = 0; c < 64; ++c) v[c] = f2bf(fp[(size_t)c << 14]);  // coalesced across lanes
        unsigned short* dst = featT + (size_t)gt * 64;
        #pragma unroll
        for (int j = 0; j < 8; ++j) {
            s16x8 pk;
            #pragma unroll
            for (int i = 0; i < 8; ++i) pk[i] = (short)v[j * 8 + i];
            *(s16x8*)(dst + j * 8) = pk;
        }
        return;
    }
    int tid = (bid - 512) * 256 + threadIdx.x;
    if (tid < 131072) {                        // one POINT per thread: 8 dis values
        const float* dp = dis + (size_t)tid * 8;
        s16x8 pk;
        #pragma unroll
        for (int j = 0; j < 8; ++j) pk[j] = (short)f2bf(dp[j]);
        *(s16x8*)(disB + (size_t)tid * 8) = pk;
        return;
    }
    int t2 = tid - 131072;
    if (t2 < 8704) {                           // W1p: kb 0..16, t 0..7, lane 0..63
        int kb   = t2 >> 9;
        int rem  = t2 & 511;
        int t    = rem >> 6;
        int lane = rem & 63;
        int row  = t * 16 + (lane & 15);
        int kbase = kb * 32 + (lane >> 4) * 8;
        s16x8 pk;
        #pragma unroll
        for (int j = 0; j < 8; ++j) {
            int kp = kbase + j;
            float val = 0.f;
            if (kp < 512) {                                          // feature weights
                int kk = kp >> 6, c = kp & 63;
                val = W1[row * 520 + kk * 65 + 1 + c];
            } else if (kp < 520) {                                   // dis weight of neighbor kp-512
                val = W1[row * 520 + (kp - 512) * 65];
            }
            pk[j] = (short)f2bf(val);
        }
        *(s16x8*)(w1p + (size_t)t2 * 8) = pk;
    } else if (t2 < 8704 + 2048) {             // W2p
        int f    = t2 - 8704;
        int kb   = f >> 9;
        int rem  = f & 511;
        int t    = rem >> 6;
        int lane = rem & 63;
        int row  = t * 16 + (lane & 15);
        int k    = kb * 32 + (lane >> 4) * 8;
        s16x8 pk;
        #pragma unroll
        for (int j = 0; j < 8; ++j) pk[j] = (short)f2bf(W2[row * 128 + k + j]);
        *(s16x8*)(w2p + (size_t)f * 8) = pk;
    } else if (t2 < 8704 + 2048 + 4096) {      // W3p
        int f    = t2 - 10752;
        int hk   = f >> 9;
        int half = hk >> 2, kb = hk & 3;
        int rem  = f & 511;
        int t    = rem >> 6;
        int lane = rem & 63;
        int row  = (half * 8 + t) * 16 + (lane & 15);
        int k    = kb * 32 + (lane >> 4) * 8;
        s16x8 pk;
        #pragma unroll
        for (int j = 0; j < 8; ++j) pk[j] = (short)f2bf(W3[row * 128 + k + j]);
        *(s16x8*)(w3p + (size_t)f * 8) = pk;
    }
}

// ---------------- main fused kernel helpers ----------------
// Plain cached loads: weight lines are shared by all 2048 waves through L2 —
// R14 proved nontemporal (nt) kills that L2 residency (served from L3, −42%).
__device__ __forceinline__ void wload4(const unsigned short* wp, int frag0, int lane,
                                       bf16x8& w0, bf16x8& w1, bf16x8& w2, bf16x8& w3)
{
    w0 = *(const bf16x8*)(wp + (size_t)((frag0 + 0) * 64 + lane) * 8);
    w1 = *(const bf16x8*)(wp + (size_t)((frag0 + 1) * 64 + lane) * 8);
    w2 = *(const bf16x8*)(wp + (size_t)((frag0 + 2) * 64 + lane) * 8);
    w3 = *(const bf16x8*)(wp + (size_t)((frag0 + 3) * 64 + lane) * 8);
}

// iq[] holds the CURRENT half of each point's idx row; swapped at the kb 7->8 boundary.
template <int KB>
__device__ __forceinline__ void gather4(const unsigned short* featB, const int4 (&iq)[4],
                                        int grp8, bf16x8& G0, bf16x8& G1, bf16x8& G2, bf16x8& G3)
{
    constexpr int kk = KB >> 1;
    constexpr int j  = kk & 3;
    const int c0 = (KB & 1) * 32 + grp8;
    G0 = *(const bf16x8*)(featB + (((size_t)(unsigned)getq(iq[0], j)) << 6) + c0);
    G1 = *(const bf16x8*)(featB + (((size_t)(unsigned)getq(iq[1], j)) << 6) + c0);
    G2 = *(const bf16x8*)(featB + (((size_t)(unsigned)getq(iq[2], j)) << 6) + c0);
    G3 = *(const bf16x8*)(featB + (((size_t)(unsigned)getq(iq[3], j)) << 6) + c0);
}

__device__ __forceinline__ void refresh_iq(int4 (&iq)[4], const int* ip0) {
    #pragma unroll
    for (int pt = 0; pt < 4; ++pt) iq[pt] = *(const int4*)(ip0 + pt * 128 + 4);   // hi half (kk 4..7)
}

// dis columns (kb=16 data): grp 0 lanes carry dis[0..7], other grps are zero pad
__device__ __forceinline__ void disload4(const unsigned short* disB, int p0, int l15, int grp,
                                         bf16x8& G0, bf16x8& G1, bf16x8& G2, bf16x8& G3)
{
    const s16x8 z = {0,0,0,0,0,0,0,0};
    if (grp == 0) {
        G0 = *(const bf16x8*)(disB + (size_t)(p0 +  0 + l15) * 8);
        G1 = *(const bf16x8*)(disB + (size_t)(p0 + 16 + l15) * 8);
        G2 = *(const bf16x8*)(disB + (size_t)(p0 + 32 + l15) * 8);
        G3 = *(const bf16x8*)(disB + (size_t)(p0 + 48 + l15) * 8);
    } else {
        G0 = __builtin_bit_cast(bf16x8, z); G1 = __builtin_bit_cast(bf16x8, z);
        G2 = __builtin_bit_cast(bf16x8, z); G3 = __builtin_bit_cast(bf16x8, z);
    }
}

__device__ __forceinline__ void dsread4(const unsigned short* strip, int kb, int l15, int grp8,
                                        bf16x8& G0, bf16x8& G1, bf16x8& G2, bf16x8& G3)
{
    G0 = *(const bf16x8*)(strip + (0 * 16 + l15) * 136 + kb * 32 + grp8);
    G1 = *(const bf16x8*)(strip + (1 * 16 + l15) * 136 + kb * 32 + grp8);
    G2 = *(const bf16x8*)(strip + (2 * 16 + l15) * 136 + kb * 32 + grp8);
    G3 = *(const bf16x8*)(strip + (3 * 16 + l15) * 136 + kb * 32 + grp8);
}

// MFMA quad wrapped with s_setprio(1): waves are independent 1-wave blocks at
// staggered phases -> scheduler favors the MFMA-entering wave (T5 regime).
__device__ __forceinline__ void mfma_quad(f32x4 (&ac)[8][4], int t0,
    const bf16x8& wa, const bf16x8& wb, const bf16x8& wc, const bf16x8& wd,
    const bf16x8& B0, const bf16x8& B1, const bf16x8& B2, const bf16x8& B3)
{
    __builtin_amdgcn_s_setprio(1);
    ac[t0+0][0] = __builtin_amdgcn_mfma_f32_16x16x32_bf16(wa, B0, ac[t0+0][0], 0, 0, 0);
    ac[t0+0][1] = __builtin_amdgcn_mfma_f32_16x16x32_bf16(wa, B1, ac[t0+0][1], 0, 0, 0);
    ac[t0+0][2] = __builtin_amdgcn_mfma_f32_16x16x32_bf16(wa, B2, ac[t0+0][2], 0, 0, 0);
    ac[t0+0][3] = __builtin_amdgcn_mfma_f32_16x16x32_bf16(wa, B3, ac[t0+0][3], 0, 0, 0);
    ac[t0+1][0] = __builtin_amdgcn_mfma_f32_16x16x32_bf16(wb, B0, ac[t0+1][0], 0, 0, 0);
    ac[t0+1][1] = __builtin_amdgcn_mfma_f32_16x16x32_bf16(wb, B1, ac[t0+1][1], 0, 0, 0);
    ac[t0+1][2] = __builtin_amdgcn_mfma_f32_16x16x32_bf16(wb, B2, ac[t0+1][2], 0, 0, 0);
    ac[t0+1][3] = __builtin_amdgcn_mfma_f32_16x16x32_bf16(wb, B3, ac[t0+1][3], 0, 0, 0);
    ac[t0+2][0] = __builtin_amdgcn_mfma_f32_16x16x32_bf16(wc, B0, ac[t0+2][0], 0, 0, 0);
    ac[t0+2][1] = __builtin_amdgcn_mfma_f32_16x16x32_bf16(wc, B1, ac[t0+2][1], 0, 0, 0);
    ac[t0+2][2] = __builtin_amdgcn_mfma_f32_16x16x32_bf16(wc, B2, ac[t0+2][2], 0, 0, 0);
    ac[t0+2][3] = __builtin_amdgcn_mfma_f32_16x16x32_bf16(wc, B3, ac[t0+2][3], 0, 0, 0);
    ac[t0+3][0] = __builtin_amdgcn_mfma_f32_16x16x32_bf16(wd, B0, ac[t0+3][0], 0, 0, 0);
    ac[t0+3][1] = __builtin_amdgcn_mfma_f32_16x16x32_bf16(wd, B1, ac[t0+3][1], 0, 0, 0);
    ac[t0+3][2] = __builtin_amdgcn_mfma_f32_16x16x32_bf16(wd, B2, ac[t0+3][2], 0, 0, 0);
    ac[t0+3][3] = __builtin_amdgcn_mfma_f32_16x16x32_bf16(wd, B3, ac[t0+3][3], 0, 0, 0);
    __builtin_amdgcn_s_setprio(0);
}

// ---------------- main fused kernel ----------------
// 1 wave per block, 64 points per wave (R12 structure = session best, exact ordering).
// Software-pipelined: gathers 2-deep reg dbuf, weights quad-dbuf, zero barriers.
// GNEXT stays AFTER the second mfma_quad (WAR rule from R11).
// 128 arch VGPR + 128 AGPR = 256 unified -> 2 waves/SIMD, all co-resident.
__global__ __launch_bounds__(64, 2) void pointconv_main(
    const unsigned short* __restrict__ featT,
    const unsigned short* __restrict__ disB,
    const int* __restrict__ idx,
    const unsigned short* __restrict__ w1p,
    const unsigned short* __restrict__ w2p,
    const unsigned short* __restrict__ w3p,
    const float* __restrict__ b1, const float* __restrict__ b2,
    const float* __restrict__ b3, float* __restrict__ out)
{
    __shared__ __align__(16) unsigned short strip[64 * 136];   // 17,408 B
    const int bid  = blockIdx.x;
    const int wg   = (bid & 7) * 256 + (bid >> 3);     // XCD-aware bijective swizzle
    const int lane = threadIdx.x;                      // 0..63
    const int grp  = lane >> 4;
    const int grp8 = grp * 8;
    const int l15  = lane & 15;
    const int p0   = wg * 64;
    const int b    = p0 >> 14;
    const int n0   = p0 & 16383;

    // pipeline registers
    bf16x8 gA0, gA1, gA2, gA3, gB0, gB1, gB2, gB3;     // B-frag double buffer
    bf16x8 wA0, wA1, wA2, wA3, wB0, wB1, wB2, wB3;     // weight quad double buffer

    // ---- prolog: first weights, idx lo-half, first two gather sets ----
    wload4(w1p, 0, lane, wA0, wA1, wA2, wA3);          // Q(0,0)

    const int* ip0 = idx + (size_t)(p0 + l15) * 8;
    int4 iq[4];
    #pragma unroll
    for (int pt = 0; pt < 4; ++pt) iq[pt] = *(const int4*)(ip0 + pt * 128);   // kk 0..3

    const unsigned short* featB = featT + ((size_t)b << 20);

    gather4<0>(featB, iq, grp8, gA0, gA1, gA2, gA3);
    gather4<1>(featB, iq, grp8, gB0, gB1, gB2, gB3);

    // ================= GEMM1: [128 x 544] * [544 x 64] =================
    f32x4 acc[8][4];
    #pragma unroll
    for (int t = 0; t < 8; ++t)
        #pragma unroll
        for (int pt = 0; pt < 4; ++pt) acc[t][pt] = (f32x4){0.f, 0.f, 0.f, 0.f};

// R12 ordering: wB load; quad1(wA,S); next-wA prefetch; quad2(wB,S); THEN gather into S's dbuf partner
#define G1_BODY(KB, S0,S1,S2,S3, WNEXT, GNEXT)                              \
    wload4(w1p, (KB)*8 + 4, lane, wB0, wB1, wB2, wB3);                      \
    mfma_quad(acc, 0, wA0, wA1, wA2, wA3, S0, S1, S2, S3);                  \
    WNEXT;                                                                  \
    mfma_quad(acc, 4, wB0, wB1, wB2, wB3, S0, S1, S2, S3);                  \
    GNEXT;

    G1_BODY(0,  gA0,gA1,gA2,gA3, wload4(w1p,  8, lane, wA0,wA1,wA2,wA3), (gather4< 2>(featB, iq, grp8, gA0,gA1,gA2,gA3)))
    G1_BODY(1,  gB0,gB1,gB2,gB3, wload4(w1p, 16, lane, wA0,wA1,wA2,wA3), (gather4< 3>(featB, iq, grp8, gB0,gB1,gB2,gB3)))
    G1_BODY(2,  gA0,gA1,gA2,gA3, wload4(w1p, 24, lane, wA0,wA1,wA2,wA3), (gather4< 4>(featB, iq, grp8, gA0,gA1,gA2,gA3)))
    G1_BODY(3,  gB0,gB1,gB2,gB3, wload4(w1p, 32, lane, wA0,wA1,wA2,wA3), (gather4< 5>(featB, iq, grp8, gB0,gB1,gB2,gB3)))
    G1_BODY(4,  gA0,gA1,gA2,gA3, wload4(w1p, 40, lane, wA0,wA1,wA2,wA3), (gather4< 6>(featB, iq, grp8, gA0,gA1,gA2,gA3)))
    G1_BODY(5,  gB0,gB1,gB2,gB3, wload4(w1p, 48, lane, wA0,wA1,wA2,wA3), (gather4< 7>(featB, iq, grp8, gB0,gB1,gB2,gB3)))
    refresh_iq(iq, ip0);                                // swap to hi half (kk 4..7)
    G1_BODY(6,  gA0,gA1,gA2,gA3, wload4(w1p, 56, lane, wA0,wA1,wA2,wA3), (gather4< 8>(featB, iq, grp8, gA0,gA1,gA2,gA3)))
    G1_BODY(7,  gB0,gB1,gB2,gB3, wload4(w1p, 64, lane, wA0,wA1,wA2,wA3), (gather4< 9>(featB, iq, grp8, gB0,gB1,gB2,gB3)))
    G1_BODY(8,  gA0,gA1,gA2,gA3, wload4(w1p, 72, lane, wA0,wA1,wA2,wA3), (gather4<10>(featB, iq, grp8, gA0,gA1,gA2,gA3)))
    G1_BODY(9,  gB0,gB1,gB2,gB3, wload4(w1p, 80, lane, wA0,wA1,wA2,wA3), (gather4<11>(featB, iq, grp8, gB0,gB1,gB2,gB3)))
    G1_BODY(10, gA0,gA1,gA2,gA3, wload4(w1p, 88, lane, wA0,wA1,wA2,wA3), (gather4<12>(featB, iq, grp8, gA0,gA1,gA2,gA3)))
    G1_BODY(11, gB0,gB1,gB2,gB3, wload4(w1p, 96, lane, wA0,wA1,wA2,wA3), (gather4<13>(featB, iq, grp8, gB0,gB1,gB2,gB3)))
    G1_BODY(12, gA0,gA1,gA2,gA3, wload4(w1p,104, lane, wA0,wA1,wA2,wA3), (gather4<14>(featB, iq, grp8, gA0,gA1,gA2,gA3)))
    G1_BODY(13, gB0,gB1,gB2,gB3, wload4(w1p,112, lane, wA0,wA1,wA2,wA3), (gather4<15>(featB, iq, grp8, gB0,gB1,gB2,gB3)))
    // kb=14: "next gather" slot loads the dis columns (kb=16 data) into the gA set
    G1_BODY(14, gA0,gA1,gA2,gA3, wload4(w1p,120, lane, wA0,wA1,wA2,wA3), disload4(disB, p0, l15, grp, gA0,gA1,gA2,gA3))
    G1_BODY(15, gB0,gB1,gB2,gB3, wload4(w1p,128, lane, wA0,wA1,wA2,wA3), )
    // kb=16 (dis/zero cols); next-weight prefetch chains into GEMM2's first quad
    G1_BODY(16, gA0,gA1,gA2,gA3, wload4(w2p, 0, lane, wA0,wA1,wA2,wA3), )
#undef G1_BODY

    // epilogue 1: bias + relu -> strip[pt][ch] bf16
    #pragma unroll
    for (int t = 0; t < 8; ++t) {
        const int chb = t * 16 + grp * 4;
        const float4 bv = *(const float4*)(b1 + chb);
        #pragma unroll
        for (int pt = 0; pt < 4; ++pt) {
            s16x4 pk;
            float v0 = acc[t][pt][0] + bv.x; pk[0] = (short)f2bf(v0 > 0.f ? v0 : 0.f);
            float v1 = acc[t][pt][1] + bv.y; pk[1] = (short)f2bf(v1 > 0.f ? v1 : 0.f);
            float v2 = acc[t][pt][2] + bv.z; pk[2] = (short)f2bf(v2 > 0.f ? v2 : 0.f);
            float v3 = acc[t][pt][3] + bv.w; pk[3] = (short)f2bf(v3 > 0.f ? v3 : 0.f);
            *(s16x4*)(strip + (pt * 16 + l15) * 136 + chb) = pk;
        }
    }

    // ================= GEMM2: [128 x 128] * [128 x 64] =================
    f32x4 acc2[8][4];
    #pragma unroll
    for (int t = 0; t < 8; ++t)
        #pragma unroll
        for (int pt = 0; pt < 4; ++pt) acc2[t][pt] = (f32x4){0.f, 0.f, 0.f, 0.f};

    dsread4(strip, 0, l15, grp8, gA0, gA1, gA2, gA3);

#define G23_BODY(WP, FR, S0,S1,S2,S3, ACC, WNEXT, DSNEXT)                   \
    wload4(WP, (FR) + 4, lane, wB0, wB1, wB2, wB3);                         \
    mfma_quad(ACC, 0, wA0, wA1, wA2, wA3, S0, S1, S2, S3);                  \
    WNEXT;                                                                  \
    DSNEXT;                                                                 \
    mfma_quad(ACC, 4, wB0, wB1, wB2, wB3, S0, S1, S2, S3);

    G23_BODY(w2p,  0, gA0,gA1,gA2,gA3, acc2, wload4(w2p,  8, lane, wA0,wA1,wA2,wA3), dsread4(strip, 1, l15, grp8, gB0,gB1,gB2,gB3))
    G23_BODY(w2p,  8, gB0,gB1,gB2,gB3, acc2, wload4(w2p, 16, lane, wA0,wA1,wA2,wA3), dsread4(strip, 2, l15, grp8, gA0,gA1,gA2,gA3))
    G23_BODY(w2p, 16, gA0,gA1,gA2,gA3, acc2, wload4(w2p, 24, lane, wA0,wA1,wA2,wA3), dsread4(strip, 3, l15, grp8, gB0,gB1,gB2,gB3))
    G23_BODY(w2p, 24, gB0,gB1,gB2,gB3, acc2, wload4(w3p,  0, lane, wA0,wA1,wA2,wA3), )

    // epilogue 2: bias + relu -> strip (H1 fully consumed; same-wave ordering)
    #pragma unroll
    for (int t = 0; t < 8; ++t) {
        const int chb = t * 16 + grp * 4;
        const float4 bv = *(const float4*)(b2 + chb);
        #pragma unroll
        for (int pt = 0; pt < 4; ++pt) {
            s16x4 pk;
            float v0 = acc2[t][pt][0] + bv.x; pk[0] = (short)f2bf(v0 > 0.f ? v0 : 0.f);
            float v1 = acc2[t][pt][1] + bv.y; pk[1] = (short)f2bf(v1 > 0.f ? v1 : 0.f);
            float v2 = acc2[t][pt][2] + bv.z; pk[2] = (short)f2bf(v2 > 0.f ? v2 : 0.f);
            float v3 = acc2[t][pt][3] + bv.w; pk[3] = (short)f2bf(v3 > 0.f ? v3 : 0.f);
            *(s16x4*)(strip + (pt * 16 + l15) * 136 + chb) = pk;
        }
    }

    // ================= GEMM3: [256 x 128] * [128 x 64], two halves =================
    #pragma unroll
    for (int half = 0; half < 2; ++half) {
        f32x4 acc3[8][4];
        #pragma unroll
        for (int t = 0; t < 8; ++t)
            #pragma unroll
            for (int pt = 0; pt < 4; ++pt) acc3[t][pt] = (f32x4){0.f, 0.f, 0.f, 0.f};

        dsread4(strip, 0, l15, grp8, gA0, gA1, gA2, gA3);
        if (half == 0) {
            G23_BODY(w3p,  0, gA0,gA1,gA2,gA3, acc3, wload4(w3p,  8, lane, wA0,wA1,wA2,wA3), dsread4(strip, 1, l15, grp8, gB0,gB1,gB2,gB3))
            G23_BODY(w3p,  8, gB0,gB1,gB2,gB3, acc3, wload4(w3p, 16, lane, wA0,wA1,wA2,wA3), dsread4(strip, 2, l15, grp8, gA0,gA1,gA2,gA3))
            G23_BODY(w3p, 16, gA0,gA1,gA2,gA3, acc3, wload4(w3p, 24, lane, wA0,wA1,wA2,wA3), dsread4(strip, 3, l15, grp8, gB0,gB1,gB2,gB3))
            G23_BODY(w3p, 24, gB0,gB1,gB2,gB3, acc3, wload4(w3p, 32, lane, wA0,wA1,wA2,wA3), )
        } else {
            G23_BODY(w3p, 32, gA0,gA1,gA2,gA3, acc3, wload4(w3p, 40, lane, wA0,wA1,wA2,wA3), dsread4(strip, 1, l15, grp8, gB0,gB1,gB2,gB3))
            G23_BODY(w3p, 40, gB0,gB1,gB2,gB3, acc3, wload4(w3p, 48, lane, wA0,wA1,wA2,wA3), dsread4(strip, 2, l15, grp8, gA0,gA1,gA2,gA3))
            G23_BODY(w3p, 48, gA0,gA1,gA2,gA3, acc3, wload4(w3p, 56, lane, wA0,wA1,wA2,wA3), dsread4(strip, 3, l15, grp8, gB0,gB1,gB2,gB3))
            G23_BODY(w3p, 56, gB0,gB1,gB2,gB3, acc3, , )
        }

        #pragma unroll
        for (int t = 0; t < 8; ++t) {
            const int chb = half * 128 + t * 16 + grp * 4;
            const float4 bv = *(const float4*)(b3 + chb);
            #pragma unroll
            for (int pt = 0; pt < 4; ++pt) {
                const int n = n0 + pt * 16 + l15;
                float* op = out + (((size_t)(b * 256 + chb)) << 14) + n;
                op[0]                  = acc3[t][pt][0] + bv.x;
                op[(size_t)1 << 14]    = acc3[t][pt][1] + bv.y;
                op[(size_t)2 << 14]    = acc3[t][pt][2] + bv.z;
                op[(size_t)3 << 14]    = acc3[t][pt][3] + bv.w;
            }
        }
    }
#undef G23_BODY
}

extern "C" void kernel_launch(void* const* d_in, const int* in_sizes, int n_in,
                              void* d_out, int out_size, void* d_ws, size_t ws_size,
                              hipStream_t stream)
{
    const float* feature = (const float*)d_in[0];
    const int*   idx     = (const int*)d_in[1];
    const float* dis     = (const float*)d_in[2];
    const float* W1      = (const float*)d_in[3];
    const float* b1      = (const float*)d_in[4];
    const float* W2      = (const float*)d_in[5];
    const float* b2      = (const float*)d_in[6];
    const float* W3      = (const float*)d_in[7];
    const float* b3      = (const float*)d_in[8];
    float* out = (float*)d_out;

    char* ws = (char*)d_ws;
    unsigned short* featT = (unsigned short*)ws;
    unsigned short* disB  = (unsigned short*)(ws + OFF_DISB);
    unsigned short* w1p   = (unsigned short*)(ws + OFF_W1B);
    unsigned short* w2p   = (unsigned short*)(ws + OFF_W2B);
    unsigned short* w3p   = (unsigned short*)(ws + OFF_W3B);

    hipLaunchKernelGGL(prep_all, dim3(1488), dim3(256), 0, stream,
                       feature, dis, W1, W2, W3, featT, disB, w1p, w2p, w3p);
    hipLaunchKernelGGL(pointconv_main, dim3(2048), dim3(64), 0, stream,
                       featT, disB, idx, w1p, w2p, w3p, b1, b2, b3, out);
}

// Round 16
// 71.180 us; speedup vs baseline: 1.5551x; 1.0265x over previous
//
#include <hip/hip_runtime.h>
#include <hip/hip_bf16.h>
#include <stdint.h>

// Problem constants
#define BB 8
#define CC 64
#define NN 16384
#define KNB 8            // neighbors
// Padded GEMM1 K (REPERMUTED): cols kk*64+c = feature[c][idx[kk]] for kk=0..7,
// cols 512..519 = dis[0..7], cols 520..543 = 0.  (17 kb-steps of 32)

typedef __attribute__((ext_vector_type(8))) short   s16x8;
typedef __attribute__((ext_vector_type(4))) short   s16x4;
typedef __attribute__((ext_vector_type(8))) __bf16  bf16x8;
typedef __attribute__((ext_vector_type(4))) float   f32x4;

__device__ __forceinline__ unsigned short f2bf(float f) {
    unsigned u = __builtin_bit_cast(unsigned, f);
    u = (u + 0x7FFFu + ((u >> 16) & 1u)) >> 16;   // RNE, inputs finite
    return (unsigned short)u;
}

__device__ __forceinline__ int getq(const int4& q, int j) {
    return j == 0 ? q.x : j == 1 ? q.y : j == 2 ? q.z : q.w;   // j constant-folds after unroll
}

// ---- workspace layout (bytes) ----
// featT [B][N][64] bf16 @ 0 ; weights frag-major @ OFF_W1B.. (disB eliminated in R16)
#define OFF_W1B   18874368u
#define OFF_W2B   19013632u
#define OFF_W3B   19046400u

// ---------------- merged prep: featT transpose + weights frag-major ----------------
// blocks 0..511: featT (feature [B][C][N] fp32 -> featT [B][N][C] bf16)
// blocks 512..569: weights (W1p 8704 thr; W2p 2048; W3p 4096 = 14848 thr = 58 blocks)
__global__ __launch_bounds__(256) void prep_all(
    const float* __restrict__ feat,
    const float* __restrict__ W1, const float* __restrict__ W2, const float* __restrict__ W3,
    unsigned short* __restrict__ featT,
    unsigned short* __restrict__ w1p, unsigned short* __restrict__ w2p,
    unsigned short* __restrict__ w3p)
{
    const int bid = blockIdx.x;
    if (bid < 512) {
        int gt = bid * 256 + threadIdx.x;          // global point 0..131071
        int b = gt >> 14, n = gt & 16383;
        const float* fp = feat + ((size_t)b << 20) + n;
        unsigned short v[64];
        #pragma unroll
        for (int c = 0; c < 64; ++c) v[c] = f2bf(fp[(size_t)c << 14]);  // coalesced across lanes
        unsigned short* dst = featT + (size_t)gt * 64;
        #pragma unroll
        for (int j = 0; j < 8; ++j) {
            s16x8 pk;
            #pragma unroll
            for (int i = 0; i < 8; ++i) pk[i] = (short)v[j * 8 + i];
            *(s16x8*)(dst + j * 8) = pk;
        }
        return;
    }
    int t2 = (bid - 512) * 256 + threadIdx.x;
    if (t2 < 8704) {                           // W1p: kb 0..16, t 0..7, lane 0..63
        int kb   = t2 >> 9;
        int rem  = t2 & 511;
        int t    = rem >> 6;
        int lane = rem & 63;
        int row  = t * 16 + (lane & 15);
        int kbase = kb * 32 + (lane >> 4) * 8;
        s16x8 pk;
        #pragma unroll
        for (int j = 0; j < 8; ++j) {
            int kp = kbase + j;
            float val = 0.f;
            if (kp < 512) {                                          // feature weights
                int kk = kp >> 6, c = kp & 63;
                val = W1[row * 520 + kk * 65 + 1 + c];
            } else if (kp < 520) {                                   // dis weight of neighbor kp-512
                val = W1[row * 520 + (kp - 512) * 65];
            }
            pk[j] = (short)f2bf(val);
        }
        *(s16x8*)(w1p + (size_t)t2 * 8) = pk;
    } else if (t2 < 8704 + 2048) {             // W2p
        int f    = t2 - 8704;
        int kb   = f >> 9;
        int rem  = f & 511;
        int t    = rem >> 6;
        int lane = rem & 63;
        int row  = t * 16 + (lane & 15);
        int k    = kb * 32 + (lane >> 4) * 8;
        s16x8 pk;
        #pragma unroll
        for (int j = 0; j < 8; ++j) pk[j] = (short)f2bf(W2[row * 128 + k + j]);
        *(s16x8*)(w2p + (size_t)f * 8) = pk;
    } else if (t2 < 8704 + 2048 + 4096) {      // W3p
        int f    = t2 - 10752;
        int hk   = f >> 9;
        int half = hk >> 2, kb = hk & 3;
        int rem  = f & 511;
        int t    = rem >> 6;
        int lane = rem & 63;
        int row  = (half * 8 + t) * 16 + (lane & 15);
        int k    = kb * 32 + (lane >> 4) * 8;
        s16x8 pk;
        #pragma unroll
        for (int j = 0; j < 8; ++j) pk[j] = (short)f2bf(W3[row * 128 + k + j]);
        *(s16x8*)(w3p + (size_t)f * 8) = pk;
    }
}

// ---------------- main fused kernel helpers ----------------
// Plain cached loads: weight lines are shared by all 2048 waves through L2 —
// R14 proved nontemporal (nt) kills that L2 residency (served from L3, −42%).
__device__ __forceinline__ void wload4(const unsigned short* wp, int frag0, int lane,
                                       bf16x8& w0, bf16x8& w1, bf16x8& w2, bf16x8& w3)
{
    w0 = *(const bf16x8*)(wp + (size_t)((frag0 + 0) * 64 + lane) * 8);
    w1 = *(const bf16x8*)(wp + (size_t)((frag0 + 1) * 64 + lane) * 8);
    w2 = *(const bf16x8*)(wp + (size_t)((frag0 + 2) * 64 + lane) * 8);
    w3 = *(const bf16x8*)(wp + (size_t)((frag0 + 3) * 64 + lane) * 8);
}

// iq[] holds the CURRENT half of each point's idx row; swapped at the kb 7->8 boundary.
template <int KB>
__device__ __forceinline__ void gather4(const unsigned short* featB, const int4 (&iq)[4],
                                        int grp8, bf16x8& G0, bf16x8& G1, bf16x8& G2, bf16x8& G3)
{
    constexpr int kk = KB >> 1;
    constexpr int j  = kk & 3;
    const int c0 = (KB & 1) * 32 + grp8;
    G0 = *(const bf16x8*)(featB + (((size_t)(unsigned)getq(iq[0], j)) << 6) + c0);
    G1 = *(const bf16x8*)(featB + (((size_t)(unsigned)getq(iq[1], j)) << 6) + c0);
    G2 = *(const bf16x8*)(featB + (((size_t)(unsigned)getq(iq[2], j)) << 6) + c0);
    G3 = *(const bf16x8*)(featB + (((size_t)(unsigned)getq(iq[3], j)) << 6) + c0);
}

__device__ __forceinline__ void refresh_iq(int4 (&iq)[4], const int* ip0) {
    #pragma unroll
    for (int pt = 0; pt < 4; ++pt) iq[pt] = *(const int4*)(ip0 + pt * 128 + 4);   // hi half (kk 4..7)
}

// 8 fp32 -> bf16x8 with the same RNE as prep (numerically identical to disB path)
__device__ __forceinline__ bf16x8 cvt8(const float* p) {
    float4 a = *(const float4*)p;
    float4 b = *(const float4*)(p + 4);
    s16x8 pk;
    pk[0] = (short)f2bf(a.x); pk[1] = (short)f2bf(a.y);
    pk[2] = (short)f2bf(a.z); pk[3] = (short)f2bf(a.w);
    pk[4] = (short)f2bf(b.x); pk[5] = (short)f2bf(b.y);
    pk[6] = (short)f2bf(b.z); pk[7] = (short)f2bf(b.w);
    return __builtin_bit_cast(bf16x8, pk);
}

// dis columns (kb=16 data): grp 0 lanes carry dis[0..7] read DIRECTLY from fp32 input
// (disB prep stage eliminated in R16); other grps are zero pad.
__device__ __forceinline__ void disload4(const float* dis, int p0, int l15, int grp,
                                         bf16x8& G0, bf16x8& G1, bf16x8& G2, bf16x8& G3)
{
    const s16x8 z = {0,0,0,0,0,0,0,0};
    if (grp == 0) {
        G0 = cvt8(dis + (size_t)(p0 +  0 + l15) * 8);
        G1 = cvt8(dis + (size_t)(p0 + 16 + l15) * 8);
        G2 = cvt8(dis + (size_t)(p0 + 32 + l15) * 8);
        G3 = cvt8(dis + (size_t)(p0 + 48 + l15) * 8);
    } else {
        G0 = __builtin_bit_cast(bf16x8, z); G1 = __builtin_bit_cast(bf16x8, z);
        G2 = __builtin_bit_cast(bf16x8, z); G3 = __builtin_bit_cast(bf16x8, z);
    }
}

__device__ __forceinline__ void dsread4(const unsigned short* strip, int kb, int l15, int grp8,
                                        bf16x8& G0, bf16x8& G1, bf16x8& G2, bf16x8& G3)
{
    G0 = *(const bf16x8*)(strip + (0 * 16 + l15) * 136 + kb * 32 + grp8);
    G1 = *(const bf16x8*)(strip + (1 * 16 + l15) * 136 + kb * 32 + grp8);
    G2 = *(const bf16x8*)(strip + (2 * 16 + l15) * 136 + kb * 32 + grp8);
    G3 = *(const bf16x8*)(strip + (3 * 16 + l15) * 136 + kb * 32 + grp8);
}

// MFMA quad wrapped with s_setprio(1): waves are independent 1-wave blocks at
// staggered phases -> scheduler favors the MFMA-entering wave (T5 regime).
__device__ __forceinline__ void mfma_quad(f32x4 (&ac)[8][4], int t0,
    const bf16x8& wa, const bf16x8& wb, const bf16x8& wc, const bf16x8& wd,
    const bf16x8& B0, const bf16x8& B1, const bf16x8& B2, const bf16x8& B3)
{
    __builtin_amdgcn_s_setprio(1);
    ac[t0+0][0] = __builtin_amdgcn_mfma_f32_16x16x32_bf16(wa, B0, ac[t0+0][0], 0, 0, 0);
    ac[t0+0][1] = __builtin_amdgcn_mfma_f32_16x16x32_bf16(wa, B1, ac[t0+0][1], 0, 0, 0);
    ac[t0+0][2] = __builtin_amdgcn_mfma_f32_16x16x32_bf16(wa, B2, ac[t0+0][2], 0, 0, 0);
    ac[t0+0][3] = __builtin_amdgcn_mfma_f32_16x16x32_bf16(wa, B3, ac[t0+0][3], 0, 0, 0);
    ac[t0+1][0] = __builtin_amdgcn_mfma_f32_16x16x32_bf16(wb, B0, ac[t0+1][0], 0, 0, 0);
    ac[t0+1][1] = __builtin_amdgcn_mfma_f32_16x16x32_bf16(wb, B1, ac[t0+1][1], 0, 0, 0);
    ac[t0+1][2] = __builtin_amdgcn_mfma_f32_16x16x32_bf16(wb, B2, ac[t0+1][2], 0, 0, 0);
    ac[t0+1][3] = __builtin_amdgcn_mfma_f32_16x16x32_bf16(wb, B3, ac[t0+1][3], 0, 0, 0);
    ac[t0+2][0] = __builtin_amdgcn_mfma_f32_16x16x32_bf16(wc, B0, ac[t0+2][0], 0, 0, 0);
    ac[t0+2][1] = __builtin_amdgcn_mfma_f32_16x16x32_bf16(wc, B1, ac[t0+2][1], 0, 0, 0);
    ac[t0+2][2] = __builtin_amdgcn_mfma_f32_16x16x32_bf16(wc, B2, ac[t0+2][2], 0, 0, 0);
    ac[t0+2][3] = __builtin_amdgcn_mfma_f32_16x16x32_bf16(wc, B3, ac[t0+2][3], 0, 0, 0);
    ac[t0+3][0] = __builtin_amdgcn_mfma_f32_16x16x32_bf16(wd, B0, ac[t0+3][0], 0, 0, 0);
    ac[t0+3][1] = __builtin_amdgcn_mfma_f32_16x16x32_bf16(wd, B1, ac[t0+3][1], 0, 0, 0);
    ac[t0+3][2] = __builtin_amdgcn_mfma_f32_16x16x32_bf16(wd, B2, ac[t0+3][2], 0, 0, 0);
    ac[t0+3][3] = __builtin_amdgcn_mfma_f32_16x16x32_bf16(wd, B3, ac[t0+3][3], 0, 0, 0);
    __builtin_amdgcn_s_setprio(0);
}

// ---------------- main fused kernel ----------------
// 1 wave per block, 64 points per wave (R12 structure = session best, exact ordering).
// Software-pipelined: gathers 2-deep reg dbuf, weights quad-dbuf, zero barriers.
// GNEXT stays AFTER the second mfma_quad (WAR rule from R11).
// 128 arch VGPR + 128 AGPR = 256 unified -> 2 waves/SIMD, all co-resident.
__global__ __launch_bounds__(64, 2) void pointconv_main(
    const unsigned short* __restrict__ featT,
    const float* __restrict__ dis,
    const int* __restrict__ idx,
    const unsigned short* __restrict__ w1p,
    const unsigned short* __restrict__ w2p,
    const unsigned short* __restrict__ w3p,
    const float* __restrict__ b1, const float* __restrict__ b2,
    const float* __restrict__ b3, float* __restrict__ out)
{
    __shared__ __align__(16) unsigned short strip[64 * 136];   // 17,408 B
    const int bid  = blockIdx.x;
    const int wg   = (bid & 7) * 256 + (bid >> 3);     // XCD-aware bijective swizzle
    const int lane = threadIdx.x;                      // 0..63
    const int grp  = lane >> 4;
    const int grp8 = grp * 8;
    const int l15  = lane & 15;
    const int p0   = wg * 64;
    const int b    = p0 >> 14;
    const int n0   = p0 & 16383;

    // pipeline registers
    bf16x8 gA0, gA1, gA2, gA3, gB0, gB1, gB2, gB3;     // B-frag double buffer
    bf16x8 wA0, wA1, wA2, wA3, wB0, wB1, wB2, wB3;     // weight quad double buffer

    // ---- prolog: first weights, idx lo-half, first two gather sets ----
    wload4(w1p, 0, lane, wA0, wA1, wA2, wA3);          // Q(0,0)

    const int* ip0 = idx + (size_t)(p0 + l15) * 8;
    int4 iq[4];
    #pragma unroll
    for (int pt = 0; pt < 4; ++pt) iq[pt] = *(const int4*)(ip0 + pt * 128);   // kk 0..3

    const unsigned short* featB = featT + ((size_t)b << 20);

    gather4<0>(featB, iq, grp8, gA0, gA1, gA2, gA3);
    gather4<1>(featB, iq, grp8, gB0, gB1, gB2, gB3);

    // ================= GEMM1: [128 x 544] * [544 x 64] =================
    f32x4 acc[8][4];
    #pragma unroll
    for (int t = 0; t < 8; ++t)
        #pragma unroll
        for (int pt = 0; pt < 4; ++pt) acc[t][pt] = (f32x4){0.f, 0.f, 0.f, 0.f};

// R12 ordering: wB load; quad1(wA,S); next-wA prefetch; quad2(wB,S); THEN gather into S's dbuf partner
#define G1_BODY(KB, S0,S1,S2,S3, WNEXT, GNEXT)                              \
    wload4(w1p, (KB)*8 + 4, lane, wB0, wB1, wB2, wB3);                      \
    mfma_quad(acc, 0, wA0, wA1, wA2, wA3, S0, S1, S2, S3);                  \
    WNEXT;                                                                  \
    mfma_quad(acc, 4, wB0, wB1, wB2, wB3, S0, S1, S2, S3);                  \
    GNEXT;

    G1_BODY(0,  gA0,gA1,gA2,gA3, wload4(w1p,  8, lane, wA0,wA1,wA2,wA3), (gather4< 2>(featB, iq, grp8, gA0,gA1,gA2,gA3)))
    G1_BODY(1,  gB0,gB1,gB2,gB3, wload4(w1p, 16, lane, wA0,wA1,wA2,wA3), (gather4< 3>(featB, iq, grp8, gB0,gB1,gB2,gB3)))
    G1_BODY(2,  gA0,gA1,gA2,gA3, wload4(w1p, 24, lane, wA0,wA1,wA2,wA3), (gather4< 4>(featB, iq, grp8, gA0,gA1,gA2,gA3)))
    G1_BODY(3,  gB0,gB1,gB2,gB3, wload4(w1p, 32, lane, wA0,wA1,wA2,wA3), (gather4< 5>(featB, iq, grp8, gB0,gB1,gB2,gB3)))
    G1_BODY(4,  gA0,gA1,gA2,gA3, wload4(w1p, 40, lane, wA0,wA1,wA2,wA3), (gather4< 6>(featB, iq, grp8, gA0,gA1,gA2,gA3)))
    G1_BODY(5,  gB0,gB1,gB2,gB3, wload4(w1p, 48, lane, wA0,wA1,wA2,wA3), (gather4< 7>(featB, iq, grp8, gB0,gB1,gB2,gB3)))
    refresh_iq(iq, ip0);                                // swap to hi half (kk 4..7)
    G1_BODY(6,  gA0,gA1,gA2,gA3, wload4(w1p, 56, lane, wA0,wA1,wA2,wA3), (gather4< 8>(featB, iq, grp8, gA0,gA1,gA2,gA3)))
    G1_BODY(7,  gB0,gB1,gB2,gB3, wload4(w1p, 64, lane, wA0,wA1,wA2,wA3), (gather4< 9>(featB, iq, grp8, gB0,gB1,gB2,gB3)))
    G1_BODY(8,  gA0,gA1,gA2,gA3, wload4(w1p, 72, lane, wA0,wA1,wA2,wA3), (gather4<10>(featB, iq, grp8, gA0,gA1,gA2,gA3)))
    G1_BODY(9,  gB0,gB1,gB2,gB3, wload4(w1p, 80, lane, wA0,wA1,wA2,wA3), (gather4<11>(featB, iq, grp8, gB0,gB1,gB2,gB3)))
    G1_BODY(10, gA0,gA1,gA2,gA3, wload4(w1p, 88, lane, wA0,wA1,wA2,wA3), (gather4<12>(featB, iq, grp8, gA0,gA1,gA2,gA3)))
    G1_BODY(11, gB0,gB1,gB2,gB3, wload4(w1p, 96, lane, wA0,wA1,wA2,wA3), (gather4<13>(featB, iq, grp8, gB0,gB1,gB2,gB3)))
    G1_BODY(12, gA0,gA1,gA2,gA3, wload4(w1p,104, lane, wA0,wA1,wA2,wA3), (gather4<14>(featB, iq, grp8, gA0,gA1,gA2,gA3)))
    G1_BODY(13, gB0,gB1,gB2,gB3, wload4(w1p,112, lane, wA0,wA1,wA2,wA3), (gather4<15>(featB, iq, grp8, gB0,gB1,gB2,gB3)))
    // kb=14: "next gather" slot converts the dis columns (kb=16 data) into the gA set
    G1_BODY(14, gA0,gA1,gA2,gA3, wload4(w1p,120, lane, wA0,wA1,wA2,wA3), disload4(dis, p0, l15, grp, gA0,gA1,gA2,gA3))
    G1_BODY(15, gB0,gB1,gB2,gB3, wload4(w1p,128, lane, wA0,wA1,wA2,wA3), )
    // kb=16 (dis/zero cols); next-weight prefetch chains into GEMM2's first quad
    G1_BODY(16, gA0,gA1,gA2,gA3, wload4(w2p, 0, lane, wA0,wA1,wA2,wA3), )
#undef G1_BODY

    // epilogue 1: bias + relu -> strip[pt][ch] bf16
    #pragma unroll
    for (int t = 0; t < 8; ++t) {
        const int chb = t * 16 + grp * 4;
        const float4 bv = *(const float4*)(b1 + chb);
        #pragma unroll
        for (int pt = 0; pt < 4; ++pt) {
            s16x4 pk;
            float v0 = acc[t][pt][0] + bv.x; pk[0] = (short)f2bf(v0 > 0.f ? v0 : 0.f);
            float v1 = acc[t][pt][1] + bv.y; pk[1] = (short)f2bf(v1 > 0.f ? v1 : 0.f);
            float v2 = acc[t][pt][2] + bv.z; pk[2] = (short)f2bf(v2 > 0.f ? v2 : 0.f);
            float v3 = acc[t][pt][3] + bv.w; pk[3] = (short)f2bf(v3 > 0.f ? v3 : 0.f);
            *(s16x4*)(strip + (pt * 16 + l15) * 136 + chb) = pk;
        }
    }

    // ================= GEMM2: [128 x 128] * [128 x 64] =================
    f32x4 acc2[8][4];
    #pragma unroll
    for (int t = 0; t < 8; ++t)
        #pragma unroll
        for (int pt = 0; pt < 4; ++pt) acc2[t][pt] = (f32x4){0.f, 0.f, 0.f, 0.f};

    dsread4(strip, 0, l15, grp8, gA0, gA1, gA2, gA3);

#define G23_BODY(WP, FR, S0,S1,S2,S3, ACC, WNEXT, DSNEXT)                   \
    wload4(WP, (FR) + 4, lane, wB0, wB1, wB2, wB3);                         \
    mfma_quad(ACC, 0, wA0, wA1, wA2, wA3, S0, S1, S2, S3);                  \
    WNEXT;                                                                  \
    DSNEXT;                                                                 \
    mfma_quad(ACC, 4, wB0, wB1, wB2, wB3, S0, S1, S2, S3);

    G23_BODY(w2p,  0, gA0,gA1,gA2,gA3, acc2, wload4(w2p,  8, lane, wA0,wA1,wA2,wA3), dsread4(strip, 1, l15, grp8, gB0,gB1,gB2,gB3))
    G23_BODY(w2p,  8, gB0,gB1,gB2,gB3, acc2, wload4(w2p, 16, lane, wA0,wA1,wA2,wA3), dsread4(strip, 2, l15, grp8, gA0,gA1,gA2,gA3))
    G23_BODY(w2p, 16, gA0,gA1,gA2,gA3, acc2, wload4(w2p, 24, lane, wA0,wA1,wA2,wA3), dsread4(strip, 3, l15, grp8, gB0,gB1,gB2,gB3))
    G23_BODY(w2p, 24, gB0,gB1,gB2,gB3, acc2, wload4(w3p,  0, lane, wA0,wA1,wA2,wA3), )

    // epilogue 2: bias + relu -> strip (H1 fully consumed; same-wave ordering)
    #pragma unroll
    for (int t = 0; t < 8; ++t) {
        const int chb = t * 16 + grp * 4;
        const float4 bv = *(const float4*)(b2 + chb);
        #pragma unroll
        for (int pt = 0; pt < 4; ++pt) {
            s16x4 pk;
            float v0 = acc2[t][pt][0] + bv.x; pk[0] = (short)f2bf(v0 > 0.f ? v0 : 0.f);
            float v1 = acc2[t][pt][1] + bv.y; pk[1] = (short)f2bf(v1 > 0.f ? v1 : 0.f);
            float v2 = acc2[t][pt][2] + bv.z; pk[2] = (short)f2bf(v2 > 0.f ? v2 : 0.f);
            float v3 = acc2[t][pt][3] + bv.w; pk[3] = (short)f2bf(v3 > 0.f ? v3 : 0.f);
            *(s16x4*)(strip + (pt * 16 + l15) * 136 + chb) = pk;
        }
    }

    // ================= GEMM3: [256 x 128] * [128 x 64], two halves =================
    #pragma unroll
    for (int half = 0; half < 2; ++half) {
        f32x4 acc3[8][4];
        #pragma unroll
        for (int t = 0; t < 8; ++t)
            #pragma unroll
            for (int pt = 0; pt < 4; ++pt) acc3[t][pt] = (f32x4){0.f, 0.f, 0.f, 0.f};

        dsread4(strip, 0, l15, grp8, gA0, gA1, gA2, gA3);
        if (half == 0) {
            G23_BODY(w3p,  0, gA0,gA1,gA2,gA3, acc3, wload4(w3p,  8, lane, wA0,wA1,wA2,wA3), dsread4(strip, 1, l15, grp8, gB0,gB1,gB2,gB3))
            G23_BODY(w3p,  8, gB0,gB1,gB2,gB3, acc3, wload4(w3p, 16, lane, wA0,wA1,wA2,wA3), dsread4(strip, 2, l15, grp8, gA0,gA1,gA2,gA3))
            G23_BODY(w3p, 16, gA0,gA1,gA2,gA3, acc3, wload4(w3p, 24, lane, wA0,wA1,wA2,wA3), dsread4(strip, 3, l15, grp8, gB0,gB1,gB2,gB3))
            G23_BODY(w3p, 24, gB0,gB1,gB2,gB3, acc3, wload4(w3p, 32, lane, wA0,wA1,wA2,wA3), )
        } else {
            G23_BODY(w3p, 32, gA0,gA1,gA2,gA3, acc3, wload4(w3p, 40, lane, wA0,wA1,wA2,wA3), dsread4(strip, 1, l15, grp8, gB0,gB1,gB2,gB3))
            G23_BODY(w3p, 40, gB0,gB1,gB2,gB3, acc3, wload4(w3p, 48, lane, wA0,wA1,wA2,wA3), dsread4(strip, 2, l15, grp8, gA0,gA1,gA2,gA3))
            G23_BODY(w3p, 48, gA0,gA1,gA2,gA3, acc3, wload4(w3p, 56, lane, wA0,wA1,wA2,wA3), dsread4(strip, 3, l15, grp8, gB0,gB1,gB2,gB3))
            G23_BODY(w3p, 56, gB0,gB1,gB2,gB3, acc3, , )
        }

        #pragma unroll
        for (int t = 0; t < 8; ++t) {
            const int chb = half * 128 + t * 16 + grp * 4;
            const float4 bv = *(const float4*)(b3 + chb);
            #pragma unroll
            for (int pt = 0; pt < 4; ++pt) {
                const int n = n0 + pt * 16 + l15;
                float* op = out + (((size_t)(b * 256 + chb)) << 14) + n;
                op[0]                  = acc3[t][pt][0] + bv.x;
                op[(size_t)1 << 14]    = acc3[t][pt][1] + bv.y;
                op[(size_t)2 << 14]    = acc3[t][pt][2] + bv.z;
                op[(size_t)3 << 14]    = acc3[t][pt][3] + bv.w;
            }
        }
    }
#undef G23_BODY
}

extern "C" void kernel_launch(void* const* d_in, const int* in_sizes, int n_in,
                              void* d_out, int out_size, void* d_ws, size_t ws_size,
                              hipStream_t stream)
{
    const float* feature = (const float*)d_in[0];
    const int*   idx     = (const int*)d_in[1];
    const float* dis     = (const float*)d_in[2];
    const float* W1      = (const float*)d_in[3];
    const float* b1      = (const float*)d_in[4];
    const float* W2      = (const float*)d_in[5];
    const float* b2      = (const float*)d_in[6];
    const float* W3      = (const float*)d_in[7];
    const float* b3      = (const float*)d_in[8];
    float* out = (float*)d_out;

    char* ws = (char*)d_ws;
    unsigned short* featT = (unsigned short*)ws;
    unsigned short* w1p   = (unsigned short*)(ws + OFF_W1B);
    unsigned short* w2p   = (unsigned short*)(ws + OFF_W2B);
    unsigned short* w3p   = (unsigned short*)(ws + OFF_W3B);

    hipLaunchKernelGGL(prep_all, dim3(570), dim3(256), 0, stream,
                       feature, W1, W2, W3, featT, w1p, w2p, w3p);
    hipLaunchKernelGGL(pointconv_main, dim3(2048), dim3(64), 0, stream,
                       featT, dis, idx, w1p, w2p, w3p, b1, b2, b3, out);
}